// Round 16
// baseline (2358.561 us; speedup 1.0000x reference)
//
#include <hip/hip_runtime.h>
#include <hip/hip_bf16.h>

#define EMB   1024
#define HID   1024
#define NBATCH 64
#define SEQ   128
#define NGATE 4096   // 4*HID
#define NBLK  128    // recurrence grid (each block owns 8 hidden units)

typedef __attribute__((ext_vector_type(8))) short bf16x8;
typedef __attribute__((ext_vector_type(4))) float f32x4;

__device__ __forceinline__ unsigned short f2bf(float f) {
    unsigned int u = __float_as_uint(f);
    unsigned int r = (u + 0x7FFFu + ((u >> 16) & 1u)) >> 16;
    return (unsigned short)r;
}

__device__ __forceinline__ bf16x8 pack8(float4 a, float4 b) {
    bf16x8 r;
    r[0] = (short)f2bf(a.x); r[1] = (short)f2bf(a.y);
    r[2] = (short)f2bf(a.z); r[3] = (short)f2bf(a.w);
    r[4] = (short)f2bf(b.x); r[5] = (short)f2bf(b.y);
    r[6] = (short)f2bf(b.z); r[7] = (short)f2bf(b.w);
    return r;
}

__device__ __forceinline__ float sigmoidf_(float x) { return 1.0f / (1.0f + __expf(-x)); }
__device__ __forceinline__ float tanhf_(float x)    { return 1.0f - 2.0f / (1.0f + __expf(2.0f * x)); }

// ---- prep kernels ------------------------------------------------------

// X[t*64+b][k] = bf16(emb[inputs[b][t]][k]);  grid 8192, block 256
__global__ void gather_x(const float* __restrict__ emb, const int* __restrict__ inp,
                         unsigned short* __restrict__ xbf) {
    int m = blockIdx.x;          // m = t*64 + b
    int t = m >> 6, b = m & 63;
    int tok = inp[b * SEQ + t];
    float4 v = ((const float4*)(emb + (long)tok * EMB))[threadIdx.x];
    ushort4 o;
    o.x = f2bf(v.x); o.y = f2bf(v.y); o.z = f2bf(v.z); o.w = f2bf(v.w);
    ((ushort4*)(xbf + (long)m * EMB))[threadIdx.x] = o;
}

// W_ih -> bf16; grid 4096, block 256
__global__ void conv_w(const float* __restrict__ w, unsigned short* __restrict__ wbf) {
    long i = (long)blockIdx.x * 1024 + (long)threadIdx.x * 4;
    float4 v = *(const float4*)(w + i);
    ushort4 o;
    o.x = f2bf(v.x); o.y = f2bf(v.y); o.z = f2bf(v.z); o.w = f2bf(v.w);
    *(ushort4*)(wbf + i) = o;
}

// bsum = b_ih + b_hh; grid 16, block 256
__global__ void bsum_k(const float* __restrict__ bi, const float* __restrict__ bh,
                       float* __restrict__ bs) {
    int i = blockIdx.x * 256 + threadIdx.x;
    bs[i] = bi[i] + bh[i];
}

// accumulate X-tile x Wih-tile: 32 MFMAs; xr = X row base (batch brow),
// wr = Wih row base (gate col nl); both bf16, L2-hot streams.
__device__ __forceinline__ void accum_x(const unsigned short* __restrict__ xr,
                                        const unsigned short* __restrict__ wr,
                                        int lk, f32x4& a0, f32x4& a1) {
#pragma unroll
    for (int kk = 0; kk < 32; kk += 2) {
        union { uint4 u4; bf16x8 v; } xa, xb, wa, wb;
        xa.u4 = *(const uint4*)(xr + kk * 32 + lk * 8);
        xb.u4 = *(const uint4*)(xr + (kk + 1) * 32 + lk * 8);
        wa.u4 = *(const uint4*)(wr + kk * 32 + lk * 8);
        wb.u4 = *(const uint4*)(wr + (kk + 1) * 32 + lk * 8);
        a0 = __builtin_amdgcn_mfma_f32_16x16x32_bf16(xa.v, wa.v, a0, 0, 0, 0);
        a1 = __builtin_amdgcn_mfma_f32_16x16x32_bf16(xb.v, wb.v, a1, 0, 0, 0);
    }
}

// ---- fused recurrence: 128 blocks x 512 thr ----------------------------
// r15 structure (hierarchical replicated flags, best: 5.63 us/step) with
// the input GEMM FUSED INTO the exchange idle: during the store/publish/
// detect window every wave computes next step's X[t+1] x W_ih tile
// (32 MFMAs, operands streamed from L2). gemm_xw + the 134MB XW buffer +
// per-step cold px HBM reads are deleted. W_hh frags register-resident;
// W_ih frags streamed (64KB/block/step, XCD-L2-resident); bias = 4 scalar
// adds in activation. acc_x double-buffered in named regs (axc/axn).
// h slot per step: 128KB, [g:128][b:64][u:8] bf16; chunk g 1KB contiguous.
// Flags: block publishes flags1[g]; leader (g%8==0) detects its 8 members,
// replicates group-done into 16 separate 64B lines; each block polls only
// its replica line (lanes 0-3) -> 32 pollers/line.
__global__ __launch_bounds__(512) void lstm_rec(const float* __restrict__ Whh,
                                                const unsigned short* __restrict__ Xbf,
                                                const unsigned short* __restrict__ Wih,
                                                const float* __restrict__ bsum,
                                                unsigned short* __restrict__ hseq,
                                                unsigned* __restrict__ flags,
                                                float* __restrict__ out) {
    __shared__ float Glds[32][68];              // [n_local][batch]
    __shared__ unsigned short Hs[64][8];        // h pack: [batch][u]

    int tid = threadIdx.x;
    int w = tid >> 6, l = tid & 63;             // wave, lane
    int lr = l & 15, lk = l >> 4;
    int bg = w & 3, ng = w >> 2;                // batch-group, gate-group
    int g = blockIdx.x;                         // owns hid g*8..g*8+7
    unsigned* flags1 = flags;                   // [128] per-block
    unsigned* flags2 = flags + 128;             // [16 reps][16 groups]
    int grp = g >> 3;                           // group 0..15
    int rep = g & 15;                           // replica line to poll
    bool leader = (g & 7) == 0;

    // W_hh fragment preload: lane lr holds gate col n_local = ng*16+lr
    int nl = ng * 16 + lr;
    int q = nl >> 3, u = nl & 7;
    long nrow = (long)(q * 1024 + g * 8 + u) * 1024;
    bf16x8 wf[32];
#pragma unroll
    for (int kk = 0; kk < 32; ++kk) {
        int k0 = kk * 32 + lk * 8;
        float4 w0 = *(const float4*)(Whh + nrow + k0);
        float4 w1 = *(const float4*)(Whh + nrow + k0 + 4);
        wf[kk] = pack8(w0, w1);
    }
    const unsigned short* wr = Wih + nrow;      // Wih stream base (same mapping)

    // bias for activation: thread owns batch b=l, hid unit g*8+w
    float bsv[4];
#pragma unroll
    for (int qq = 0; qq < 4; ++qq)
        bsv[qq] = bsum[qq * 1024 + g * 8 + w];

    float c = 0.0f;
    int brow = bg * 16 + lr;                    // batch row for A-fragments

    // acc_x for t=0 (X row t*64+brow)
    f32x4 axc0 = {0.f, 0.f, 0.f, 0.f}, axc1 = {0.f, 0.f, 0.f, 0.f};
    accum_x(Xbf + (long)brow * 1024, wr, lk, axc0, axc1);

    for (int t = 0; t < SEQ; ++t) {
        const uint4* hc = (const uint4*)hseq + (long)t * 8192;  // slot t

        // h-part MFMA (slot 0 is zeros -> correct at t=0)
        f32x4 ah0 = {0.f, 0.f, 0.f, 0.f}, ah1 = {0.f, 0.f, 0.f, 0.f};
#pragma unroll
        for (int kk = 0; kk < 32; kk += 2) {
            union { uint4 u4; bf16x8 v; } ua, ub;
            ua.u4 = hc[(kk * 4 + lk) * 64 + brow];
            ub.u4 = hc[((kk + 1) * 4 + lk) * 64 + brow];
            ah0 = __builtin_amdgcn_mfma_f32_16x16x32_bf16(ua.v, wf[kk],     ah0, 0, 0, 0);
            ah1 = __builtin_amdgcn_mfma_f32_16x16x32_bf16(ub.v, wf[kk + 1], ah1, 0, 0, 0);
        }
        f32x4 gacc = (axc0 + axc1) + (ah0 + ah1);
        // D: col(n)=lr, row(batch)=lk*4+r -> Glds[ng*16+lr][bg*16+lk*4+r]
        *(f32x4*)&Glds[ng * 16 + lr][bg * 16 + lk * 4] = gacc;
        __syncthreads();

        // activation: thread owns batch b=l, hid unit g*8+w
        float p[4];
#pragma unroll
        for (int qq = 0; qq < 4; ++qq)
            p[qq] = Glds[qq * 8 + w][l] + bsv[qq];
        float ig = sigmoidf_(p[0]);
        float fg = sigmoidf_(p[1]);
        float gg = tanhf_(p[2]);
        float og = sigmoidf_(p[3]);
        c = fg * c + ig * gg;
        float h = og * tanhf_(c);

        if (t == SEQ - 1) {
            out[l * HID + g * 8 + w] = h;
            out[NBATCH * HID + l * HID + g * 8 + w] = c;
        } else {
            Hs[l][w] = f2bf(h);
            __syncthreads();                    // pack barrier (Hs complete)
            unsigned tv = (unsigned)(t + 1);

            if (tid < 64) {   // wave 0: store -> ack -> publish (-> leader detect)
                unsigned long long* hn = (unsigned long long*)hseq +
                                         (long)(t + 1) * 16384 + (long)g * 128;
                const unsigned long long* hsu = (const unsigned long long*)Hs;
                __hip_atomic_store(&hn[tid * 2],     hsu[tid * 2],
                                   __ATOMIC_RELAXED, __HIP_MEMORY_SCOPE_AGENT);
                __hip_atomic_store(&hn[tid * 2 + 1], hsu[tid * 2 + 1],
                                   __ATOMIC_RELAXED, __HIP_MEMORY_SCOPE_AGENT);
                asm volatile("s_waitcnt vmcnt(0)" ::: "memory");  // ONLY the 2 stores
                if (tid == 0)
                    __hip_atomic_store(&flags1[g], tv,
                                       __ATOMIC_RELAXED, __HIP_MEMORY_SCOPE_AGENT);
                if (leader) {
                    if (tid < 2) {
                        const unsigned* fp = flags1 + g + tid * 4;
                        long spins = 0;
                        for (;;) {
                            uint4 fv;
                            asm volatile("global_load_dwordx4 %0, %1, off sc0 sc1\n\t"
                                         "s_waitcnt vmcnt(0)"
                                         : "=v"(fv) : "v"(fp) : "memory");
                            __builtin_amdgcn_sched_barrier(0);
                            unsigned mn  = fv.x < fv.y ? fv.x : fv.y;
                            unsigned mn2 = fv.z < fv.w ? fv.z : fv.w;
                            if (mn2 < mn) mn = mn2;
                            if (mn >= tv) break;
                            if (++spins > 500000L) break;
                            __builtin_amdgcn_s_sleep(1);
                        }
                    }
                    // reconverged: group done -> write 16 replica lines
                    if (tid < 16)
                        __hip_atomic_store(&flags2[tid * 16 + grp], tv,
                                           __ATOMIC_RELAXED, __HIP_MEMORY_SCOPE_AGENT);
                }
            }

            // ALL waves: fused input-GEMM for step t+1 (fills the poll idle)
            f32x4 axn0 = {0.f, 0.f, 0.f, 0.f}, axn1 = {0.f, 0.f, 0.f, 0.f};
            accum_x(Xbf + ((long)(t + 1) * 64 + brow) * 1024, wr, lk, axn0, axn1);

            if (tid < 4) {   // wave 0: poll own replica line (32 pollers/line)
                const unsigned* fp = flags2 + rep * 16 + tid * 4;
                long spins = 0;
                for (;;) {
                    uint4 fv;
                    asm volatile("global_load_dwordx4 %0, %1, off sc0 sc1\n\t"
                                 "s_waitcnt vmcnt(0)"
                                 : "=v"(fv) : "v"(fp) : "memory");
                    __builtin_amdgcn_sched_barrier(0);
                    unsigned mn  = fv.x < fv.y ? fv.x : fv.y;
                    unsigned mn2 = fv.z < fv.w ? fv.z : fv.w;
                    if (mn2 < mn) mn = mn2;
                    if (mn >= tv) break;
                    if (++spins > 500000L) break;
                    __builtin_amdgcn_s_sleep(1);
                }
            }
            __syncthreads();            // all waves gated on wave 0's detect
            axc0 = axn0; axc1 = axn1;   // static-named swap (no dyn indexing)
        }
    }
}

// ---- launch ------------------------------------------------------------
extern "C" void kernel_launch(void* const* d_in, const int* in_sizes, int n_in,
                              void* d_out, int out_size, void* d_ws, size_t ws_size,
                              hipStream_t stream) {
    const float* emb  = (const float*)d_in[0];
    const float* W_ih = (const float*)d_in[1];
    const float* W_hh = (const float*)d_in[2];
    const float* b_ih = (const float*)d_in[3];
    const float* b_hh = (const float*)d_in[4];
    const int*   inp  = (const int*)d_in[5];
    float* out = (float*)d_out;

    // workspace layout (~41 MiB; XW buffer deleted)
    char* ws = (char*)d_ws;
    unsigned short* Xbf  = (unsigned short*)ws;                   //  16,777,216 B
    unsigned short* Wbf  = (unsigned short*)(ws + 16777216);      //   8,388,608 B
    float*          bs   = (float*)(ws + 25165824);               //      16,384 B
    unsigned short* hseq = (unsigned short*)(ws + 25182208);      //  16,777,216 B
    unsigned*       flags= (unsigned*)(ws + 41959424);            //       1,536 B

    hipMemsetAsync(flags, 0, 1536, stream);
    hipMemsetAsync(hseq, 0, NBATCH * HID * sizeof(unsigned short), stream);  // slot 0
    gather_x<<<SEQ * NBATCH, 256, 0, stream>>>(emb, inp, Xbf);
    conv_w<<<NGATE, 256, 0, stream>>>(W_ih, Wbf);
    bsum_k<<<16, 256, 0, stream>>>(b_ih, b_hh, bs);
    lstm_rec<<<NBLK, 512, 0, stream>>>(W_hh, Xbf, Wbf, bs, hseq, flags, out);
}

// Round 17
// 804.465 us; speedup vs baseline: 2.9318x; 2.9318x over previous
//
#include <hip/hip_runtime.h>
#include <hip/hip_bf16.h>

#define EMB   1024
#define HID   1024
#define NBATCH 64
#define SEQ   128
#define NGATE 4096   // 4*HID
#define NBLK  128    // recurrence grid (each block owns 8 hidden units)

typedef __attribute__((ext_vector_type(8))) short bf16x8;
typedef __attribute__((ext_vector_type(4))) float f32x4;

__device__ __forceinline__ unsigned short f2bf(float f) {
    unsigned int u = __float_as_uint(f);
    unsigned int r = (u + 0x7FFFu + ((u >> 16) & 1u)) >> 16;
    return (unsigned short)r;
}

__device__ __forceinline__ bf16x8 pack8(float4 a, float4 b) {
    bf16x8 r;
    r[0] = (short)f2bf(a.x); r[1] = (short)f2bf(a.y);
    r[2] = (short)f2bf(a.z); r[3] = (short)f2bf(a.w);
    r[4] = (short)f2bf(b.x); r[5] = (short)f2bf(b.y);
    r[6] = (short)f2bf(b.z); r[7] = (short)f2bf(b.w);
    return r;
}

__device__ __forceinline__ float sigmoidf_(float x) { return 1.0f / (1.0f + __expf(-x)); }
__device__ __forceinline__ float tanhf_(float x)    { return 1.0f - 2.0f / (1.0f + __expf(2.0f * x)); }

// ---- prep kernels ------------------------------------------------------

// X[t*64+b][k] = bf16(emb[inputs[b][t]][k]);  grid 8192, block 256
__global__ void gather_x(const float* __restrict__ emb, const int* __restrict__ inp,
                         unsigned short* __restrict__ xbf) {
    int m = blockIdx.x;          // m = t*64 + b
    int t = m >> 6, b = m & 63;
    int tok = inp[b * SEQ + t];
    float4 v = ((const float4*)(emb + (long)tok * EMB))[threadIdx.x];
    ushort4 o;
    o.x = f2bf(v.x); o.y = f2bf(v.y); o.z = f2bf(v.z); o.w = f2bf(v.w);
    ((ushort4*)(xbf + (long)m * EMB))[threadIdx.x] = o;
}

// W_ih -> bf16; grid 4096, block 256
__global__ void conv_w(const float* __restrict__ w, unsigned short* __restrict__ wbf) {
    long i = (long)blockIdx.x * 1024 + (long)threadIdx.x * 4;
    float4 v = *(const float4*)(w + i);
    ushort4 o;
    o.x = f2bf(v.x); o.y = f2bf(v.y); o.z = f2bf(v.z); o.w = f2bf(v.w);
    *(ushort4*)(wbf + i) = o;
}

// bsum = b_ih + b_hh; grid 16, block 256
__global__ void bsum_k(const float* __restrict__ bi, const float* __restrict__ bh,
                       float* __restrict__ bs) {
    int i = blockIdx.x * 256 + threadIdx.x;
    bs[i] = bi[i] + bh[i];
}

// ---- input GEMM: XW[t][n][b] = sum_k X[t*64+b][k]*W_ih[n][k] + bsum[n] ----
__global__ __launch_bounds__(256) void gemm_xw(const unsigned short* __restrict__ A,
                                               const unsigned short* __restrict__ Bw,
                                               const float* __restrict__ bsum,
                                               float* __restrict__ XW) {
    __shared__ unsigned short As[128][40];
    __shared__ unsigned short Bs[128][40];
    int bx = blockIdx.x;             // N tile (0..31)
    int by = blockIdx.y;             // M tile (0..63)
    int tid = threadIdx.x;
    int w = tid >> 6, l = tid & 63;
    int wm = w >> 1, wn = w & 1;
    int lr = l & 15, lk = l >> 4;

    f32x4 acc[4][4];
#pragma unroll
    for (int ni = 0; ni < 4; ++ni) {
        float bsv = bsum[bx * 128 + wn * 64 + ni * 16 + lr];
#pragma unroll
        for (int mi = 0; mi < 4; ++mi) {
            acc[mi][ni][0] = bsv; acc[mi][ni][1] = bsv;
            acc[mi][ni][2] = bsv; acc[mi][ni][3] = bsv;
        }
    }

    int sr = tid >> 1;
    int sc = (tid & 1) * 16;
    const unsigned short* ga = A  + (long)(by * 128 + sr) * 1024 + sc;
    const unsigned short* gb = Bw + (long)(bx * 128 + sr) * 1024 + sc;

    for (int kt = 0; kt < 32; ++kt) {
        uint4 va0 = *(const uint4*)(ga);
        uint4 va1 = *(const uint4*)(ga + 8);
        uint4 vb0 = *(const uint4*)(gb);
        uint4 vb1 = *(const uint4*)(gb + 8);
        *(uint4*)&As[sr][sc]     = va0;
        *(uint4*)&As[sr][sc + 8] = va1;
        *(uint4*)&Bs[sr][sc]     = vb0;
        *(uint4*)&Bs[sr][sc + 8] = vb1;
        __syncthreads();

        bf16x8 af[4], bfr[4];
#pragma unroll
        for (int mi = 0; mi < 4; ++mi)
            af[mi] = *(const bf16x8*)&As[wm * 64 + mi * 16 + lr][lk * 8];
#pragma unroll
        for (int ni = 0; ni < 4; ++ni)
            bfr[ni] = *(const bf16x8*)&Bs[wn * 64 + ni * 16 + lr][lk * 8];
#pragma unroll
        for (int mi = 0; mi < 4; ++mi)
#pragma unroll
            for (int ni = 0; ni < 4; ++ni)
                acc[mi][ni] = __builtin_amdgcn_mfma_f32_16x16x32_bf16(af[mi], bfr[ni], acc[mi][ni], 0, 0, 0);
        __syncthreads();
        ga += 32; gb += 32;
    }

#pragma unroll
    for (int mi = 0; mi < 4; ++mi) {
        int mg = by * 128 + wm * 64 + mi * 16 + lk * 4;
        int tt = mg >> 6;
        int bb = mg & 63;
#pragma unroll
        for (int ni = 0; ni < 4; ++ni) {
            int nn = bx * 128 + wn * 64 + ni * 16 + lr;
            *(f32x4*)(XW + (long)tt * (NGATE * 64) + (long)nn * 64 + bb) = acc[mi][ni];
        }
    }
}

// ---- recurrence: 128 blocks x 512 thr, hierarchical flag exchange ------
// Best measured structure (r15: 5.63 us/step). Stage 1 -- block g publishes
// flags1[g] (polled only by its group leader, 16 leaders x 2 lanes);
// stage 2 -- leader (g%8==0) detects its 8 members, then REPLICATES the
// group-done flag into 16 separate 64B lines; every block polls ONLY its
// replica line (lanes 0-3) -> 32 pollers per line (kills same-line MALL
// queueing, the +1.1 us hidden term found in r15).
// h slot per step: 128KB, [g:128][b:64][u:8] bf16; chunk g 1KB contiguous;
// reader A-fragment = ONE 16B uint4. hseq virgin region; cached reads are
// flag-gated so never stale. px (XW fp32) prefetch at TOP of step.
__global__ __launch_bounds__(512) void lstm_rec(const float* __restrict__ Whh,
                                                const float* __restrict__ XW,
                                                unsigned short* __restrict__ hseq,
                                                unsigned* __restrict__ flags,
                                                float* __restrict__ out) {
    __shared__ float Glds[32][68];              // [n_local][batch]
    __shared__ unsigned short Hs[64][8];        // h pack: [batch][u]

    int tid = threadIdx.x;
    int w = tid >> 6, l = tid & 63;             // wave, lane
    int lr = l & 15, lk = l >> 4;
    int bg = w & 3, ng = w >> 2;                // batch-group, gate-group
    int g = blockIdx.x;                         // owns hid g*8..g*8+7
    unsigned* flags1 = flags;                   // [128] per-block
    unsigned* flags2 = flags + 128;             // [16 reps][16 groups]
    int grp = g >> 3;                           // group 0..15
    int rep = g & 15;                           // replica line to poll
    bool leader = (g & 7) == 0;

    // W_hh fragment preload: lane lr holds gate col n_local = ng*16+lr
    int nl = ng * 16 + lr;
    int q = nl >> 3, u = nl & 7;
    long nrow = (long)(q * 1024 + g * 8 + u) * 1024;
    bf16x8 wf[32];
#pragma unroll
    for (int kk = 0; kk < 32; ++kk) {
        int k0 = kk * 32 + lk * 8;
        float4 w0 = *(const float4*)(Whh + nrow + k0);
        float4 w1 = *(const float4*)(Whh + nrow + k0 + 4);
        wf[kk] = pack8(w0, w1);
    }

    float c = 0.0f;
    int brow = bg * 16 + lr;                    // batch row for A-fragments

    for (int t = 0; t < SEQ; ++t) {
        const uint4* hc = (const uint4*)hseq + (long)t * 8192;  // slot t

        // px prefetch for THIS step (hidden under the MFMA phase; drains at
        // the Glds barrier). thread: b=l, hid unit g*8+w
        float px[4];
#pragma unroll
        for (int qq = 0; qq < 4; ++qq)
            px[qq] = XW[(long)t * (NGATE * 64) +
                        (long)(qq * 1024 + g * 8 + w) * 64 + l];

        // MFMA: wave (bg,ng) -> batches bg*16.. x gate cols ng*16..
        // frag kk: producing block g' = kk*4+lk; one uint4 = 8 hid of brow
        f32x4 acc0 = {0.f, 0.f, 0.f, 0.f}, acc1 = {0.f, 0.f, 0.f, 0.f};
#pragma unroll
        for (int kk = 0; kk < 32; kk += 2) {
            union { uint4 u4; bf16x8 v; } ua, ub;
            ua.u4 = hc[(kk * 4 + lk) * 64 + brow];
            ub.u4 = hc[((kk + 1) * 4 + lk) * 64 + brow];
            acc0 = __builtin_amdgcn_mfma_f32_16x16x32_bf16(ua.v, wf[kk],     acc0, 0, 0, 0);
            acc1 = __builtin_amdgcn_mfma_f32_16x16x32_bf16(ub.v, wf[kk + 1], acc1, 0, 0, 0);
        }
        f32x4 gacc = acc0 + acc1;
        // D: col(n)=lr, row(batch)=lk*4+r -> Glds[ng*16+lr][bg*16+lk*4+r]
        *(f32x4*)&Glds[ng * 16 + lr][bg * 16 + lk * 4] = gacc;
        __syncthreads();

        // activation: thread owns batch b=l, hid unit g*8+w
        float p[4];
#pragma unroll
        for (int qq = 0; qq < 4; ++qq)
            p[qq] = Glds[qq * 8 + w][l] + px[qq];
        float ig = sigmoidf_(p[0]);
        float fg = sigmoidf_(p[1]);
        float gg = tanhf_(p[2]);
        float og = sigmoidf_(p[3]);
        c = fg * c + ig * gg;
        float h = og * tanhf_(c);

        if (t == SEQ - 1) {
            out[l * HID + g * 8 + w] = h;
            out[NBATCH * HID + l * HID + g * 8 + w] = c;
        } else {
            Hs[l][w] = f2bf(h);
            __syncthreads();                    // pack barrier (Hs complete)
            unsigned tv = (unsigned)(t + 1);

            if (tid < 64) {   // wave 0 runs the whole exchange
                // --- store h chunk; ack; publish flags1[g] ---
                unsigned long long* hn = (unsigned long long*)hseq +
                                         (long)(t + 1) * 16384 + (long)g * 128;
                const unsigned long long* hsu = (const unsigned long long*)Hs;
                __hip_atomic_store(&hn[tid * 2],     hsu[tid * 2],
                                   __ATOMIC_RELAXED, __HIP_MEMORY_SCOPE_AGENT);
                __hip_atomic_store(&hn[tid * 2 + 1], hsu[tid * 2 + 1],
                                   __ATOMIC_RELAXED, __HIP_MEMORY_SCOPE_AGENT);
                asm volatile("s_waitcnt vmcnt(0)" ::: "memory");  // ONLY the 2 stores
                if (tid == 0)
                    __hip_atomic_store(&flags1[g], tv,
                                       __ATOMIC_RELAXED, __HIP_MEMORY_SCOPE_AGENT);

                // --- stage 1 (leaders only): detect group, replicate ---
                if (leader) {
                    if (tid < 2) {
                        const unsigned* fp = flags1 + g + tid * 4;
                        long spins = 0;
                        for (;;) {
                            uint4 fv;
                            asm volatile("global_load_dwordx4 %0, %1, off sc0 sc1\n\t"
                                         "s_waitcnt vmcnt(0)"
                                         : "=v"(fv) : "v"(fp) : "memory");
                            __builtin_amdgcn_sched_barrier(0);
                            unsigned mn  = fv.x < fv.y ? fv.x : fv.y;
                            unsigned mn2 = fv.z < fv.w ? fv.z : fv.w;
                            if (mn2 < mn) mn = mn2;
                            if (mn >= tv) break;
                            if (++spins > 500000L) break;
                            __builtin_amdgcn_s_sleep(1);
                        }
                    }
                    // reconverged: group done -> write 16 replica lines
                    if (tid < 16)
                        __hip_atomic_store(&flags2[tid * 16 + grp], tv,
                                           __ATOMIC_RELAXED, __HIP_MEMORY_SCOPE_AGENT);
                }

                // --- stage 2 (all blocks): poll own replica line ---
                if (tid < 4) {
                    const unsigned* fp = flags2 + rep * 16 + tid * 4;
                    long spins = 0;
                    for (;;) {
                        uint4 fv;
                        asm volatile("global_load_dwordx4 %0, %1, off sc0 sc1\n\t"
                                     "s_waitcnt vmcnt(0)"
                                     : "=v"(fv) : "v"(fp) : "memory");
                        __builtin_amdgcn_sched_barrier(0);
                        unsigned mn  = fv.x < fv.y ? fv.x : fv.y;
                        unsigned mn2 = fv.z < fv.w ? fv.z : fv.w;
                        if (mn2 < mn) mn = mn2;
                        if (mn >= tv) break;
                        if (++spins > 500000L) break;
                        __builtin_amdgcn_s_sleep(1);
                    }
                }
            }
            __syncthreads();            // all waves gated on wave 0's detect
        }
    }
}

// ---- launch ------------------------------------------------------------
extern "C" void kernel_launch(void* const* d_in, const int* in_sizes, int n_in,
                              void* d_out, int out_size, void* d_ws, size_t ws_size,
                              hipStream_t stream) {
    const float* emb  = (const float*)d_in[0];
    const float* W_ih = (const float*)d_in[1];
    const float* W_hh = (const float*)d_in[2];
    const float* b_ih = (const float*)d_in[3];
    const float* b_hh = (const float*)d_in[4];
    const int*   inp  = (const int*)d_in[5];
    float* out = (float*)d_out;

    // workspace layout (~176 MiB; hseq its own virgin region)
    char* ws = (char*)d_ws;
    float*          XW   = (float*)ws;                            // 134,217,728 B
    unsigned short* Xbf  = (unsigned short*)(ws + 134217728);     //  16,777,216 B
    unsigned short* Wbf  = (unsigned short*)(ws + 150994944);     //   8,388,608 B
    float*          bs   = (float*)(ws + 159383552);              //      16,384 B
    unsigned short* hseq = (unsigned short*)(ws + 159399936);     //  16,777,216 B
    unsigned*       flags= (unsigned*)(ws + 176177152);           //  1,536 B (flags1+flags2)

    hipMemsetAsync(flags, 0, 1536, stream);
    hipMemsetAsync(hseq, 0, NBATCH * HID * sizeof(unsigned short), stream);  // slot 0
    gather_x<<<SEQ * NBATCH, 256, 0, stream>>>(emb, inp, Xbf);
    conv_w<<<NGATE, 256, 0, stream>>>(W_ih, Wbf);
    bsum_k<<<16, 256, 0, stream>>>(b_ih, b_hh, bs);
    gemm_xw<<<dim3(32, 64), 256, 0, stream>>>(Xbf, Wbf, bs, XW);
    lstm_rec<<<NBLK, 512, 0, stream>>>(W_hh, XW, hseq, flags, out);
}